// Round 22
// baseline (235.651 us; speedup 1.0000x reference)
//
#include <hip/hip_runtime.h>

#define BIG_NEG_F (-4294967296.0f)

typedef __attribute__((ext_vector_type(8))) short bf16x8;
typedef __attribute__((ext_vector_type(4))) float f32x4;

__device__ __forceinline__ float wave_sum(float v) {
#pragma unroll
    for (int m = 32; m; m >>= 1) v += __shfl_xor(v, m, 64);
    return v;
}
__device__ __forceinline__ float wave_max(float v) {
#pragma unroll
    for (int m = 32; m; m >>= 1) v = fmaxf(v, __shfl_xor(v, m, 64));
    return v;
}

__device__ __forceinline__ unsigned int pack2(float a, float b) {
    return (__float_as_uint(b) & 0xffff0000u) | (__float_as_uint(a) >> 16);
}
__device__ __forceinline__ float hipart(float x) {
    return __uint_as_float(__float_as_uint(x) & 0xffff0000u);
}
// split float4s into hi/lo bf16 (truncation split: hi exact-representable, lo = residual)
__device__ __forceinline__ void store_pair(unsigned short* hp, unsigned short* lp,
                                           float4 a, float4 b) {
    uint4 h;
    h.x = pack2(a.x, a.y); h.y = pack2(a.z, a.w);
    h.z = pack2(b.x, b.y); h.w = pack2(b.z, b.w);
    float lax = a.x - hipart(a.x), lay = a.y - hipart(a.y);
    float laz = a.z - hipart(a.z), law = a.w - hipart(a.w);
    float lbx = b.x - hipart(b.x), lby = b.y - hipart(b.y);
    float lbz = b.z - hipart(b.z), lbw = b.w - hipart(b.w);
    uint4 l;
    l.x = pack2(lax, lay); l.y = pack2(laz, law);
    l.z = pack2(lbx, lby); l.w = pack2(lbz, lbw);
    *(uint4*)hp = h;
    *(uint4*)lp = l;
}

// Fused prep: mask-mode detect (u8/i32/i64), x = seq*keep, q = ln1(x).
// WAVE-PER-ROW: 512 blocks x 4 waves; one wave = one row (64 lanes x float4).
__global__ __launch_bounds__(256) void prep_ln_kernel(const float* __restrict__ seq,
                                                      const unsigned char* __restrict__ mraw,
                                                      unsigned char* __restrict__ mout,
                                                      float* __restrict__ X, float* __restrict__ Q,
                                                      const float* __restrict__ g,
                                                      const float* __restrict__ be) {
    __shared__ int flags[2];
    int tid = threadIdx.x, w = tid >> 6, lane = tid & 63;
    if (tid == 0) { flags[0] = 0; flags[1] = 0; }
    __syncthreads();
    for (int i = tid; i < 2048; i += 256) {
        if (mraw[i]) {
            if (i & 3) atomicOr(&flags[0], 1);
            else if (i & 4) atomicOr(&flags[1], 1);
        }
    }
    __syncthreads();
    int mode = flags[0] ? 0 : (flags[1] ? 1 : 2);  // 0=u8, 1=i32, 2=i64
    int row = blockIdx.x * 4 + w;
    unsigned char mrow = (mode == 0) ? mraw[row] : (mode == 1) ? mraw[row * 4] : mraw[row * 8];
    if (lane == 0) mout[row] = mrow ? 1 : 0;
    int idx = row * 256 + lane * 4;
    float4 v;
    if (mrow) { v.x = 0.f; v.y = 0.f; v.z = 0.f; v.w = 0.f; }
    else v = *(const float4*)(seq + idx);
    *(float4*)(X + idx) = v;
    float mean = wave_sum(v.x + v.y + v.z + v.w) * (1.f / 256.f);
    float4 d;
    d.x = v.x - mean; d.y = v.y - mean; d.z = v.z - mean; d.w = v.w - mean;
    float var = wave_sum(d.x * d.x + d.y * d.y + d.z * d.z + d.w * d.w) * (1.f / 256.f);
    float inv = 1.f / sqrtf(var + 1e-8f);
    float4 gv = *(const float4*)(g + lane * 4);
    float4 bv = *(const float4*)(be + lane * 4);
    float4 o;
    o.x = d.x * inv * gv.x + bv.x;
    o.y = d.y * inv * gv.y + bv.y;
    o.z = d.z * inv * gv.z + bv.z;
    o.w = d.w * inv * gv.w + bv.w;
    *(float4*)(Q + idx) = o;
}

// WAVE-PER-ROW layernorm: 512 blocks x 4 waves, float4 loads, zero barriers.
__global__ __launch_bounds__(256) void ln_kernel(const float* __restrict__ X, float* __restrict__ Y,
                                                 const float* __restrict__ g,
                                                 const float* __restrict__ be) {
    int tid = threadIdx.x, w = tid >> 6, lane = tid & 63;
    int row = blockIdx.x * 4 + w;
    int idx = row * 256 + lane * 4;
    float4 v = *(const float4*)(X + idx);
    float mean = wave_sum(v.x + v.y + v.z + v.w) * (1.f / 256.f);
    float4 d;
    d.x = v.x - mean; d.y = v.y - mean; d.z = v.z - mean; d.w = v.w - mean;
    float var = wave_sum(d.x * d.x + d.y * d.y + d.z * d.z + d.w * d.w) * (1.f / 256.f);
    float inv = 1.f / sqrtf(var + 1e-8f);
    float4 gv = *(const float4*)(g + lane * 4);
    float4 bv = *(const float4*)(be + lane * 4);
    float4 o;
    o.x = d.x * inv * gv.x + bv.x;
    o.y = d.y * inv * gv.y + bv.y;
    o.z = d.z * inv * gv.z + bv.z;
    o.w = d.w * inv * gv.w + bv.w;
    *(float4*)(Y + idx) = o;
}

struct GemmJob {
    const float* A;            // [2048,256]
    const float* W;            // [256,256] row-major (out,in)
    const float* bias;         // [256]
    const float* pos;          // [256,256] per-position add, or null
    const float* res;          // residual add, or null
    const unsigned char* maskm;// row mask (zero out), or null
    float* C;                  // [2048,256]
    int relu;
};

// MFMA GEMM, 32x64 tile — the measured optimum (64x64 too few blocks, 16x64 too much
// re-staging: r15/r16/r17 = 249/236.8/239.4). 4 waves as 2Mx2N, each wave 16x32
// (2 frags, 12 MFMA/K-tile). BK=64, split-precision bf16 (A·B ≈ Ah·Bh+Ah·Bl+Al·Bh,
// rel err ~2^-16), fragment layouts HW-verified r11. LDS 27.6KB. Register-prefetch.
__global__ __launch_bounds__(256) void gemm_mfma_kernel(GemmJob j0, GemmJob j1, GemmJob j2) {
    GemmJob J = (blockIdx.z == 0) ? j0 : (blockIdx.z == 1 ? j1 : j2);
    __shared__ unsigned short Ah[32][72], Al[32][72], Wh[64][72], Wl[64][72];
    int tid = threadIdx.x;
    int n0 = blockIdx.x * 64, m0 = blockIdx.y * 32;
    int w = tid >> 6, lane = tid & 63;
    int wm = w >> 1, wn = w & 1;
    int rowA = tid >> 3, kA = (tid & 7) * 8;    // A staging: 32 rows x 64 k, 8 floats/thread
    int rowW = tid >> 2, kW = (tid & 3) * 16;   // W staging: 64 rows x 64 k, 16 floats/thread
    const float* Asrc = J.A + (m0 + rowA) * 256 + kA;
    const float* Wsrc = J.W + (n0 + rowW) * 256 + kW;
    float4 ar0 = *(const float4*)(Asrc), ar1 = *(const float4*)(Asrc + 4);
    float4 wr0 = *(const float4*)(Wsrc),      wr1 = *(const float4*)(Wsrc + 4),
           wr2 = *(const float4*)(Wsrc + 8),  wr3 = *(const float4*)(Wsrc + 12);
    f32x4 acc[2] = {};
    int r15 = lane & 15, hgrp = (lane >> 4) << 3;
    for (int kt = 0; kt < 4; ++kt) {
        if (kt) __syncthreads();                // previous compute done before overwrite
        store_pair(&Ah[rowA][kA],     &Al[rowA][kA],     ar0, ar1);
        store_pair(&Wh[rowW][kW],     &Wl[rowW][kW],     wr0, wr1);
        store_pair(&Wh[rowW][kW + 8], &Wl[rowW][kW + 8], wr2, wr3);
        __syncthreads();
        if (kt < 3) {                           // prefetch next K-tile; retires under MFMAs
            int ko = (kt + 1) * 64;
            ar0 = *(const float4*)(Asrc + ko);      ar1 = *(const float4*)(Asrc + ko + 4);
            wr0 = *(const float4*)(Wsrc + ko);      wr1 = *(const float4*)(Wsrc + ko + 4);
            wr2 = *(const float4*)(Wsrc + ko + 8);  wr3 = *(const float4*)(Wsrc + ko + 12);
        }
#pragma unroll
        for (int s = 0; s < 2; ++s) {
            int ko = s * 32 + hgrp;
            bf16x8 ah = *(const bf16x8*)&Ah[wm * 16 + r15][ko];
            bf16x8 al = *(const bf16x8*)&Al[wm * 16 + r15][ko];
            bf16x8 bh0 = *(const bf16x8*)&Wh[wn * 32 + r15][ko];
            bf16x8 bh1 = *(const bf16x8*)&Wh[wn * 32 + 16 + r15][ko];
            bf16x8 bl0 = *(const bf16x8*)&Wl[wn * 32 + r15][ko];
            bf16x8 bl1 = *(const bf16x8*)&Wl[wn * 32 + 16 + r15][ko];
            acc[0] = __builtin_amdgcn_mfma_f32_16x16x32_bf16(ah, bh0, acc[0], 0, 0, 0);
            acc[0] = __builtin_amdgcn_mfma_f32_16x16x32_bf16(ah, bl0, acc[0], 0, 0, 0);
            acc[0] = __builtin_amdgcn_mfma_f32_16x16x32_bf16(al, bh0, acc[0], 0, 0, 0);
            acc[1] = __builtin_amdgcn_mfma_f32_16x16x32_bf16(ah, bh1, acc[1], 0, 0, 0);
            acc[1] = __builtin_amdgcn_mfma_f32_16x16x32_bf16(ah, bl1, acc[1], 0, 0, 0);
            acc[1] = __builtin_amdgcn_mfma_f32_16x16x32_bf16(al, bh1, acc[1], 0, 0, 0);
        }
    }
    // epilogue: C/D layout col=lane&15, row=(lane>>4)*4+rr
#pragma unroll
    for (int nf = 0; nf < 2; ++nf) {
        int col = n0 + wn * 32 + nf * 16 + r15;
        int rowb = m0 + wm * 16 + ((lane >> 4) << 2);
        float bcol = J.bias[col];
        f32x4 a = acc[nf];
#pragma unroll
        for (int rr = 0; rr < 4; ++rr) {
            int m = rowb + rr;
            float v = a[rr] + bcol;
            if (J.pos) v += J.pos[(m & 255) * 256 + col];
            if (J.relu) v = fmaxf(v, 0.f);
            if (J.res) v += J.res[m * 256 + col];
            if (J.maskm && J.maskm[m]) v = 0.f;
            J.C[m * 256 + col] = v;
        }
    }
}

// PAIRED attn, 8 WAVES (512 threads), launch_bounds(512,4): r21 proved 8 waves lifts
// occupancy 25->51% but (512,8)'s 64-VGPR cap spilled (WRITE 2->13MB), canceling the
// gain. (512,4) = 128-VGPR budget: the ~52-VGPR inner loop fits with no scratch, and
// occupancy is unchanged (grid 1024 -> 4 blocks/CU x 8 waves = 2048 threads/CU = HW
// max). k ≡ w (mod 8); pairing's 25% traffic cut kept; softmax 8 waves = 2q x 4 heads;
// combine 512 threads. LDS ~29KB x4 = 116KB. Spill tripwire: WRITE must be 2048KB.
__global__ __launch_bounds__(512, 4) void attn_kernel(
    const float* __restrict__ Q, const float* __restrict__ Kp, const float* __restrict__ Vp,
    const float* __restrict__ qres, const int* __restrict__ tm,
    const float* __restrict__ tK, const float* __restrict__ tV,
    const float* __restrict__ g2, const float* __restrict__ b2,
    float* __restrict__ X2) {
    int bid = (int)blockIdx.x;
    int b = bid & 7;                    // XCD-aligned batch
    int i6 = bid >> 3;                  // 0..127
    int j = i6 & 31, a = i6 >> 5;
    int base = 2 * j + (a >> 1);        // 0..63
    int P = (a & 1) ? base : 127 - base;
    int qA = 2 * P, qB = 2 * P + 1;
    int tid = threadIdx.x, w = tid >> 6, lane = tid & 63;
    __shared__ float qrow[2][256];
    __shared__ int   stm[2][256];
    __shared__ float p[2][4][264];
    __shared__ float opart[2][8][256];
    __shared__ float denom[2][4];
    __shared__ float lnws[16];
    __shared__ float lnvw[16];

    int rowbaseA = (b * 256 + qA) * 256;
    int rowbaseB = (b * 256 + qB) * 256;
    {
        int pr = tid >> 8, ix = tid & 255;          // 512 threads cover 2x256
        int rb = pr ? rowbaseB : rowbaseA;
        qrow[pr][ix] = Q[rb + ix];
        int t = tm[rb + ix];
        stm[pr][ix] = t < 0 ? 0 : (t > 512 ? 512 : t);
    }
    __syncthreads();

    // --- phase 1: scores for BOTH q, k ≡ w (mod 8); batch-2, shared K loads
    {
        int h = lane >> 4;
        const float* qrA = &qrow[0][lane * 4];
        const float* qrB = &qrow[1][lane * 4];
        float qA0 = qrA[0], qA1 = qrA[1], qA2 = qrA[2], qA3 = qrA[3];
        float qB0 = qrB[0], qB1 = qrB[1], qB2 = qrB[2], qB3 = qrB[3];
        const float* Kb  = Kp + (size_t)(b << 8) * 256 + lane * 4;
        const float* tKb = tK + lane * 4;
        int nact = (qB >= w) ? ((qB - w) >> 3) + 1 : 0;   // #k in {w, w+8, ...} <= qB
        int i = 0;
        for (; i + 2 <= nact; i += 2) {
            int k0 = w + 8 * i, k1 = k0 + 8;
            float4 kv0 = *(const float4*)(Kb + k0 * 256);
            float4 kv1 = *(const float4*)(Kb + k1 * 256);
            float4 tA0 = *(const float4*)(tKb + stm[0][k0] * 256);
            float4 tA1 = *(const float4*)(tKb + stm[0][k1] * 256);
            float4 tB0 = *(const float4*)(tKb + stm[1][k0] * 256);
            float4 tB1 = *(const float4*)(tKb + stm[1][k1] * 256);
            float sA0 = qA0 * (kv0.x + tA0.x) + qA1 * (kv0.y + tA0.y) + qA2 * (kv0.z + tA0.z) + qA3 * (kv0.w + tA0.w);
            float sA1 = qA0 * (kv1.x + tA1.x) + qA1 * (kv1.y + tA1.y) + qA2 * (kv1.z + tA1.z) + qA3 * (kv1.w + tA1.w);
            float sB0 = qB0 * (kv0.x + tB0.x) + qB1 * (kv0.y + tB0.y) + qB2 * (kv0.z + tB0.z) + qB3 * (kv0.w + tB0.w);
            float sB1 = qB0 * (kv1.x + tB1.x) + qB1 * (kv1.y + tB1.y) + qB2 * (kv1.z + tB1.z) + qB3 * (kv1.w + tB1.w);
            sA0 += __shfl_xor(sA0, 1, 64); sA1 += __shfl_xor(sA1, 1, 64);
            sB0 += __shfl_xor(sB0, 1, 64); sB1 += __shfl_xor(sB1, 1, 64);
            sA0 += __shfl_xor(sA0, 2, 64); sA1 += __shfl_xor(sA1, 2, 64);
            sB0 += __shfl_xor(sB0, 2, 64); sB1 += __shfl_xor(sB1, 2, 64);
            sA0 += __shfl_xor(sA0, 4, 64); sA1 += __shfl_xor(sA1, 4, 64);
            sB0 += __shfl_xor(sB0, 4, 64); sB1 += __shfl_xor(sB1, 4, 64);
            sA0 += __shfl_xor(sA0, 8, 64); sA1 += __shfl_xor(sA1, 8, 64);
            sB0 += __shfl_xor(sB0, 8, 64); sB1 += __shfl_xor(sB1, 8, 64);
            if ((lane & 15) == 0) {
                p[0][h][k0] = sA0 * 0.125f;
                p[0][h][k1] = sA1 * 0.125f;
                p[1][h][k0] = sB0 * 0.125f;
                p[1][h][k1] = sB1 * 0.125f;
            }
        }
        if (i < nact) {
            int k = w + 8 * i;
            float4 kv = *(const float4*)(Kb + k * 256);
            float4 tA4 = *(const float4*)(tKb + stm[0][k] * 256);
            float4 tB4 = *(const float4*)(tKb + stm[1][k] * 256);
            float sA = qA0 * (kv.x + tA4.x) + qA1 * (kv.y + tA4.y) + qA2 * (kv.z + tA4.z) + qA3 * (kv.w + tA4.w);
            float sB = qB0 * (kv.x + tB4.x) + qB1 * (kv.y + tB4.y) + qB2 * (kv.z + tB4.z) + qB3 * (kv.w + tB4.w);
            sA += __shfl_xor(sA, 1, 64); sB += __shfl_xor(sB, 1, 64);
            sA += __shfl_xor(sA, 2, 64); sB += __shfl_xor(sB, 2, 64);
            sA += __shfl_xor(sA, 4, 64); sB += __shfl_xor(sB, 4, 64);
            sA += __shfl_xor(sA, 8, 64); sB += __shfl_xor(sB, 8, 64);
            if ((lane & 15) == 0) {
                p[0][h][k] = sA * 0.125f;
                p[1][h][k] = sB * 0.125f;
            }
        }
    }
    __syncthreads();

    // --- softmax: 8 waves = 2 q x 4 heads. invalid k -> e = 0.
    {
        int pr = w >> 2, hh = w & 3;
        int qp = pr ? qB : qA;
        float* ph = &p[pr][hh][0];
        float v0 = (lane       <= qp) ? ph[lane      ] : BIG_NEG_F;
        float v1 = (lane + 64  <= qp) ? ph[lane + 64 ] : BIG_NEG_F;
        float v2 = (lane + 128 <= qp) ? ph[lane + 128] : BIG_NEG_F;
        float v3 = (lane + 192 <= qp) ? ph[lane + 192] : BIG_NEG_F;
        float mx = wave_max(fmaxf(fmaxf(v0, v1), fmaxf(v2, v3)));
        float e0 = (lane       <= qp) ? __expf(v0 - mx) : 0.f;
        float e1 = (lane + 64  <= qp) ? __expf(v1 - mx) : 0.f;
        float e2 = (lane + 128 <= qp) ? __expf(v2 - mx) : 0.f;
        float e3 = (lane + 192 <= qp) ? __expf(v3 - mx) : 0.f;
        ph[lane] = e0; ph[lane + 64] = e1; ph[lane + 128] = e2; ph[lane + 192] = e3;
        float ssum = wave_sum(e0 + e1 + e2 + e3);
        if (lane == 0) denom[pr][hh] = ssum;
    }
    __syncthreads();

    // --- phase 3: PV for BOTH q, k ≡ w (mod 8); batch-2, shared V loads
    {
        int hh = lane >> 4;
        const float* Vb  = Vp + (size_t)(b << 8) * 256 + lane * 4;
        const float* tVb = tV + lane * 4;
        const float* prA = &p[0][hh][0];
        const float* prB = &p[1][hh][0];
        float4 aA0 = {0.f, 0.f, 0.f, 0.f}, aA1 = aA0, aB0 = aA0, aB1 = aA0;
        int cnt = (qB >= w) ? ((qB - w) >> 3) + 1 : 0;
        int i = 0;
        for (; i + 2 <= cnt; i += 2) {
            int k0 = w + 8 * i, k1 = k0 + 8;
            float pA0 = prA[k0], pA1 = prA[k1], pB0 = prB[k0], pB1 = prB[k1];
            float4 v0 = *(const float4*)(Vb + k0 * 256);
            float4 v1 = *(const float4*)(Vb + k1 * 256);
            float4 uA0 = *(const float4*)(tVb + stm[0][k0] * 256);
            float4 uA1 = *(const float4*)(tVb + stm[0][k1] * 256);
            float4 uB0 = *(const float4*)(tVb + stm[1][k0] * 256);
            float4 uB1 = *(const float4*)(tVb + stm[1][k1] * 256);
            aA0.x += pA0 * (v0.x + uA0.x); aA0.y += pA0 * (v0.y + uA0.y); aA0.z += pA0 * (v0.z + uA0.z); aA0.w += pA0 * (v0.w + uA0.w);
            aA1.x += pA1 * (v1.x + uA1.x); aA1.y += pA1 * (v1.y + uA1.y); aA1.z += pA1 * (v1.z + uA1.z); aA1.w += pA1 * (v1.w + uA1.w);
            aB0.x += pB0 * (v0.x + uB0.x); aB0.y += pB0 * (v0.y + uB0.y); aB0.z += pB0 * (v0.z + uB0.z); aB0.w += pB0 * (v0.w + uB0.w);
            aB1.x += pB1 * (v1.x + uB1.x); aB1.y += pB1 * (v1.y + uB1.y); aB1.z += pB1 * (v1.z + uB1.z); aB1.w += pB1 * (v1.w + uB1.w);
        }
        if (i < cnt) {
            int k2 = w + 8 * i;
            float pA = prA[k2], pB = prB[k2];
            float4 v = *(const float4*)(Vb + k2 * 256);
            float4 uA = *(const float4*)(tVb + stm[0][k2] * 256);
            float4 uB = *(const float4*)(tVb + stm[1][k2] * 256);
            aA0.x += pA * (v.x + uA.x); aA0.y += pA * (v.y + uA.y);
            aA0.z += pA * (v.z + uA.z); aA0.w += pA * (v.w + uA.w);
            aB0.x += pB * (v.x + uB.x); aB0.y += pB * (v.y + uB.y);
            aB0.z += pB * (v.z + uB.z); aB0.w += pB * (v.w + uB.w);
        }
        float4 oA, oB;
        oA.x = aA0.x + aA1.x; oA.y = aA0.y + aA1.y; oA.z = aA0.z + aA1.z; oA.w = aA0.w + aA1.w;
        oB.x = aB0.x + aB1.x; oB.y = aB0.y + aB1.y; oB.z = aB0.z + aB1.z; oB.w = aB0.w + aB1.w;
        *(float4*)&opart[0][w][lane * 4] = oA;
        *(float4*)&opart[1][w][lane * 4] = oB;
    }
    __syncthreads();

    // --- combine + fused ln2: 512 threads cover both rows; 2 barriers
    {
        int pr = tid >> 8, d = tid & 255;
        int rb = pr ? rowbaseB : rowbaseA;
        float tot = opart[pr][0][d] + opart[pr][1][d] + opart[pr][2][d] + opart[pr][3][d]
                  + opart[pr][4][d] + opart[pr][5][d] + opart[pr][6][d] + opart[pr][7][d];
        float xv = qres[rb + d] + tot / denom[pr][d >> 6];
        float s = wave_sum(xv);
        if (lane == 0) lnws[w] = s;
        __syncthreads();
        int wb = pr * 4;
        float mean = (lnws[wb] + lnws[wb + 1] + lnws[wb + 2] + lnws[wb + 3]) * (1.f / 256.f);
        float dd = xv - mean;
        float s2 = wave_sum(dd * dd);
        if (lane == 0) lnvw[w] = s2;
        __syncthreads();
        float var = (lnvw[wb] + lnvw[wb + 1] + lnvw[wb + 2] + lnvw[wb + 3]) * (1.f / 256.f);
        X2[rb + d] = dd / sqrtf(var + 1e-8f) * g2[d] + b2[d];
    }
}

extern "C" void kernel_launch(void* const* d_in, const int* in_sizes, int n_in,
                              void* d_out, int out_size, void* d_ws, size_t ws_size,
                              hipStream_t stream) {
    const unsigned char* mask_raw = (const unsigned char*)d_in[0];
    const float* seq  = (const float*)d_in[1];
    const int*   tm   = (const int*)d_in[3];
    const float* Wq   = (const float*)d_in[5];
    const float* bq   = (const float*)d_in[6];
    const float* Wk   = (const float*)d_in[7];
    const float* bk   = (const float*)d_in[8];
    const float* Wv   = (const float*)d_in[9];
    const float* bv   = (const float*)d_in[10];
    const float* ln1g = (const float*)d_in[11];
    const float* ln1b = (const float*)d_in[12];
    const float* ln2g = (const float*)d_in[13];
    const float* ln2b = (const float*)d_in[14];
    const float* W1   = (const float*)d_in[15];
    const float* b1   = (const float*)d_in[16];
    const float* W2   = (const float*)d_in[17];
    const float* b2   = (const float*)d_in[18];
    const float* posK = (const float*)d_in[19];
    const float* posV = (const float*)d_in[20];
    const float* tK   = (const float*)d_in[21];
    const float* tV   = (const float*)d_in[22];
    const float* lnfg = (const float*)d_in[23];
    const float* lnfb = (const float*)d_in[24];

    const int NEL = 8 * 256 * 256;
    float* x   = (float*)d_ws;
    float* q   = x   + NEL;
    float* Qb  = q   + NEL;
    float* KpB = Qb  + NEL;
    float* VpB = KpB + NEL;
    float* x2  = VpB + NEL;
    float* hb  = x2  + NEL;
    unsigned char* mask = (unsigned char*)(hb + NEL);

    dim3 gQKV(4, 64, 3);   // 32x64 tiles: 768 blocks = 3/CU
    dim3 gFFN(4, 64, 1);   // 256 blocks = 1/CU

    prep_ln_kernel<<<512, 256, 0, stream>>>(seq, mask_raw, mask, x, q, ln1g, ln1b);
    for (int blk = 0; blk < 2; ++blk) {
        int o1 = blk * 256, oW = blk * 256 * 256;
        GemmJob jq = {q, Wq + oW, bq + o1, nullptr, nullptr, nullptr, Qb, 0};
        GemmJob jk = {x, Wk + oW, bk + o1, posK,    nullptr, nullptr, KpB, 0};
        GemmJob jv = {x, Wv + oW, bv + o1, posV,    nullptr, nullptr, VpB, 0};
        gemm_mfma_kernel<<<gQKV, 256, 0, stream>>>(jq, jk, jv);
        attn_kernel<<<1024, 512, 0, stream>>>(Qb, KpB, VpB, q, tm, tK, tV,
                                              ln2g + o1, ln2b + o1, x2);
        GemmJob f1 = {x2, W1 + oW, b1 + o1, nullptr, nullptr, nullptr, hb, 1};
        gemm_mfma_kernel<<<gFFN, 256, 0, stream>>>(f1, f1, f1);
        GemmJob f2 = {hb, W2 + oW, b2 + o1, nullptr, x2, mask, x, 0};
        gemm_mfma_kernel<<<gFFN, 256, 0, stream>>>(f2, f2, f2);
        if (blk == 0) ln_kernel<<<512, 256, 0, stream>>>(x, q, ln1g + 256, ln1b + 256);
    }
    ln_kernel<<<512, 256, 0, stream>>>(x, (float*)d_out, lnfg, lnfb);
}

// Round 23
// 233.944 us; speedup vs baseline: 1.0073x; 1.0073x over previous
//
#include <hip/hip_runtime.h>

#define BIG_NEG_F (-4294967296.0f)

typedef __attribute__((ext_vector_type(8))) short bf16x8;
typedef __attribute__((ext_vector_type(4))) float f32x4;

__device__ __forceinline__ float wave_sum(float v) {
#pragma unroll
    for (int m = 32; m; m >>= 1) v += __shfl_xor(v, m, 64);
    return v;
}
__device__ __forceinline__ float wave_max(float v) {
#pragma unroll
    for (int m = 32; m; m >>= 1) v = fmaxf(v, __shfl_xor(v, m, 64));
    return v;
}

__device__ __forceinline__ unsigned int pack2(float a, float b) {
    return (__float_as_uint(b) & 0xffff0000u) | (__float_as_uint(a) >> 16);
}
__device__ __forceinline__ float hipart(float x) {
    return __uint_as_float(__float_as_uint(x) & 0xffff0000u);
}
// split float4s into hi/lo bf16 (truncation split: hi exact-representable, lo = residual)
__device__ __forceinline__ void store_pair(unsigned short* hp, unsigned short* lp,
                                           float4 a, float4 b) {
    uint4 h;
    h.x = pack2(a.x, a.y); h.y = pack2(a.z, a.w);
    h.z = pack2(b.x, b.y); h.w = pack2(b.z, b.w);
    float lax = a.x - hipart(a.x), lay = a.y - hipart(a.y);
    float laz = a.z - hipart(a.z), law = a.w - hipart(a.w);
    float lbx = b.x - hipart(b.x), lby = b.y - hipart(b.y);
    float lbz = b.z - hipart(b.z), lbw = b.w - hipart(b.w);
    uint4 l;
    l.x = pack2(lax, lay); l.y = pack2(laz, law);
    l.z = pack2(lbx, lby); l.w = pack2(lbz, lbw);
    *(uint4*)hp = h;
    *(uint4*)lp = l;
}
__device__ __forceinline__ void store_one(unsigned short* hp, unsigned short* lp, float4 a) {
    uint2 h, l;
    h.x = pack2(a.x, a.y); h.y = pack2(a.z, a.w);
    l.x = pack2(a.x - hipart(a.x), a.y - hipart(a.y));
    l.y = pack2(a.z - hipart(a.z), a.w - hipart(a.w));
    *(uint2*)hp = h;
    *(uint2*)lp = l;
}

// Fused prep: mask-mode detect (u8/i32/i64), x = seq*keep, q = ln1(x).
// WAVE-PER-ROW: 512 blocks x 4 waves; one wave = one row (64 lanes x float4).
__global__ __launch_bounds__(256) void prep_ln_kernel(const float* __restrict__ seq,
                                                      const unsigned char* __restrict__ mraw,
                                                      unsigned char* __restrict__ mout,
                                                      float* __restrict__ X, float* __restrict__ Q,
                                                      const float* __restrict__ g,
                                                      const float* __restrict__ be) {
    __shared__ int flags[2];
    int tid = threadIdx.x, w = tid >> 6, lane = tid & 63;
    if (tid == 0) { flags[0] = 0; flags[1] = 0; }
    __syncthreads();
    for (int i = tid; i < 2048; i += 256) {
        if (mraw[i]) {
            if (i & 3) atomicOr(&flags[0], 1);
            else if (i & 4) atomicOr(&flags[1], 1);
        }
    }
    __syncthreads();
    int mode = flags[0] ? 0 : (flags[1] ? 1 : 2);  // 0=u8, 1=i32, 2=i64
    int row = blockIdx.x * 4 + w;
    unsigned char mrow = (mode == 0) ? mraw[row] : (mode == 1) ? mraw[row * 4] : mraw[row * 8];
    if (lane == 0) mout[row] = mrow ? 1 : 0;
    int idx = row * 256 + lane * 4;
    float4 v;
    if (mrow) { v.x = 0.f; v.y = 0.f; v.z = 0.f; v.w = 0.f; }
    else v = *(const float4*)(seq + idx);
    *(float4*)(X + idx) = v;
    float mean = wave_sum(v.x + v.y + v.z + v.w) * (1.f / 256.f);
    float4 d;
    d.x = v.x - mean; d.y = v.y - mean; d.z = v.z - mean; d.w = v.w - mean;
    float var = wave_sum(d.x * d.x + d.y * d.y + d.z * d.z + d.w * d.w) * (1.f / 256.f);
    float inv = 1.f / sqrtf(var + 1e-8f);
    float4 gv = *(const float4*)(g + lane * 4);
    float4 bv = *(const float4*)(be + lane * 4);
    float4 o;
    o.x = d.x * inv * gv.x + bv.x;
    o.y = d.y * inv * gv.y + bv.y;
    o.z = d.z * inv * gv.z + bv.z;
    o.w = d.w * inv * gv.w + bv.w;
    *(float4*)(Q + idx) = o;
}

// WAVE-PER-ROW layernorm: 512 blocks x 4 waves, float4 loads, zero barriers.
__global__ __launch_bounds__(256) void ln_kernel(const float* __restrict__ X, float* __restrict__ Y,
                                                 const float* __restrict__ g,
                                                 const float* __restrict__ be) {
    int tid = threadIdx.x, w = tid >> 6, lane = tid & 63;
    int row = blockIdx.x * 4 + w;
    int idx = row * 256 + lane * 4;
    float4 v = *(const float4*)(X + idx);
    float mean = wave_sum(v.x + v.y + v.z + v.w) * (1.f / 256.f);
    float4 d;
    d.x = v.x - mean; d.y = v.y - mean; d.z = v.z - mean; d.w = v.w - mean;
    float var = wave_sum(d.x * d.x + d.y * d.y + d.z * d.z + d.w * d.w) * (1.f / 256.f);
    float inv = 1.f / sqrtf(var + 1e-8f);
    float4 gv = *(const float4*)(g + lane * 4);
    float4 bv = *(const float4*)(be + lane * 4);
    float4 o;
    o.x = d.x * inv * gv.x + bv.x;
    o.y = d.y * inv * gv.y + bv.y;
    o.z = d.z * inv * gv.z + bv.z;
    o.w = d.w * inv * gv.w + bv.w;
    *(float4*)(Y + idx) = o;
}

struct GemmJob {
    const float* A;            // [2048,256]
    const float* W;            // [256,256] row-major (out,in)
    const float* bias;         // [256]
    const float* pos;          // [256,256] per-position add, or null
    const float* res;          // residual add, or null
    const unsigned char* maskm;// row mask (zero out), or null
    float* C;                  // [2048,256]
    int relu;
};

// MFMA GEMM, 32x64 tile — measured optimum for QKV (r15/r16/r17 = 249/236.8/239.4).
// 4 waves as 2Mx2N, each wave 16x32 (2 frags, 12 MFMA/K-tile). BK=64, split-precision
// bf16 (A·B ≈ Ah·Bh+Ah·Bl+Al·Bh, rel err ~2^-16), fragment layouts HW-verified r11.
// LDS 27.6KB. Register-prefetch of next K-tile under the MFMAs.
__global__ __launch_bounds__(256) void gemm_mfma_kernel(GemmJob j0, GemmJob j1, GemmJob j2) {
    GemmJob J = (blockIdx.z == 0) ? j0 : (blockIdx.z == 1 ? j1 : j2);
    __shared__ unsigned short Ah[32][72], Al[32][72], Wh[64][72], Wl[64][72];
    int tid = threadIdx.x;
    int n0 = blockIdx.x * 64, m0 = blockIdx.y * 32;
    int w = tid >> 6, lane = tid & 63;
    int wm = w >> 1, wn = w & 1;
    int rowA = tid >> 3, kA = (tid & 7) * 8;    // A staging: 32 rows x 64 k, 8 floats/thread
    int rowW = tid >> 2, kW = (tid & 3) * 16;   // W staging: 64 rows x 64 k, 16 floats/thread
    const float* Asrc = J.A + (m0 + rowA) * 256 + kA;
    const float* Wsrc = J.W + (n0 + rowW) * 256 + kW;
    float4 ar0 = *(const float4*)(Asrc), ar1 = *(const float4*)(Asrc + 4);
    float4 wr0 = *(const float4*)(Wsrc),      wr1 = *(const float4*)(Wsrc + 4),
           wr2 = *(const float4*)(Wsrc + 8),  wr3 = *(const float4*)(Wsrc + 12);
    f32x4 acc[2] = {};
    int r15 = lane & 15, hgrp = (lane >> 4) << 3;
    for (int kt = 0; kt < 4; ++kt) {
        if (kt) __syncthreads();                // previous compute done before overwrite
        store_pair(&Ah[rowA][kA],     &Al[rowA][kA],     ar0, ar1);
        store_pair(&Wh[rowW][kW],     &Wl[rowW][kW],     wr0, wr1);
        store_pair(&Wh[rowW][kW + 8], &Wl[rowW][kW + 8], wr2, wr3);
        __syncthreads();
        if (kt < 3) {                           // prefetch next K-tile; retires under MFMAs
            int ko = (kt + 1) * 64;
            ar0 = *(const float4*)(Asrc + ko);      ar1 = *(const float4*)(Asrc + ko + 4);
            wr0 = *(const float4*)(Wsrc + ko);      wr1 = *(const float4*)(Wsrc + ko + 4);
            wr2 = *(const float4*)(Wsrc + ko + 8);  wr3 = *(const float4*)(Wsrc + ko + 12);
        }
#pragma unroll
        for (int s = 0; s < 2; ++s) {
            int ko = s * 32 + hgrp;
            bf16x8 ah = *(const bf16x8*)&Ah[wm * 16 + r15][ko];
            bf16x8 al = *(const bf16x8*)&Al[wm * 16 + r15][ko];
            bf16x8 bh0 = *(const bf16x8*)&Wh[wn * 32 + r15][ko];
            bf16x8 bh1 = *(const bf16x8*)&Wh[wn * 32 + 16 + r15][ko];
            bf16x8 bl0 = *(const bf16x8*)&Wl[wn * 32 + r15][ko];
            bf16x8 bl1 = *(const bf16x8*)&Wl[wn * 32 + 16 + r15][ko];
            acc[0] = __builtin_amdgcn_mfma_f32_16x16x32_bf16(ah, bh0, acc[0], 0, 0, 0);
            acc[0] = __builtin_amdgcn_mfma_f32_16x16x32_bf16(ah, bl0, acc[0], 0, 0, 0);
            acc[0] = __builtin_amdgcn_mfma_f32_16x16x32_bf16(al, bh0, acc[0], 0, 0, 0);
            acc[1] = __builtin_amdgcn_mfma_f32_16x16x32_bf16(ah, bh1, acc[1], 0, 0, 0);
            acc[1] = __builtin_amdgcn_mfma_f32_16x16x32_bf16(ah, bl1, acc[1], 0, 0, 0);
            acc[1] = __builtin_amdgcn_mfma_f32_16x16x32_bf16(al, bh1, acc[1], 0, 0, 0);
        }
    }
    // epilogue: C/D layout col=lane&15, row=(lane>>4)*4+rr
#pragma unroll
    for (int nf = 0; nf < 2; ++nf) {
        int col = n0 + wn * 32 + nf * 16 + r15;
        int rowb = m0 + wm * 16 + ((lane >> 4) << 2);
        float bcol = J.bias[col];
        f32x4 a = acc[nf];
#pragma unroll
        for (int rr = 0; rr < 4; ++rr) {
            int m = rowb + rr;
            float v = a[rr] + bcol;
            if (J.pos) v += J.pos[(m & 255) * 256 + col];
            if (J.relu) v = fmaxf(v, 0.f);
            if (J.res) v += J.res[m * 256 + col];
            if (J.maskm && J.maskm[m]) v = 0.f;
            J.C[m * 256 + col] = v;
        }
    }
}

// MFMA GEMM, 16x64 tile — FFN ONLY (untested cell from r17: the combined QKV+FFN
// move to 16x64 regressed, likely from QKV's tripled W re-staging; FFN at 32x64 is
// the worst-occupied dispatch left at 256 blocks = 1.0/CU, zero co-residency).
// 512 blocks = 2/CU. 4 waves, each one 16x16 col-tile (6 MFMA/K-tile). LDS 23KB.
__global__ __launch_bounds__(256) void gemm_mfma16_kernel(GemmJob J) {
    __shared__ unsigned short Ah[16][72], Al[16][72], Wh[64][72], Wl[64][72];
    int tid = threadIdx.x;
    int n0 = blockIdx.x * 64, m0 = blockIdx.y * 16;
    int w = tid >> 6, lane = tid & 63;
    int rowA = tid >> 4, kA = (tid & 15) * 4;   // A staging: 16 rows x 64 k, 4 floats/thread
    int rowW = tid >> 2, kW = (tid & 3) * 16;   // W staging: 64 rows x 64 k, 16 floats/thread
    const float* Asrc = J.A + (m0 + rowA) * 256 + kA;
    const float* Wsrc = J.W + (n0 + rowW) * 256 + kW;
    float4 ar0 = *(const float4*)(Asrc);
    float4 wr0 = *(const float4*)(Wsrc),      wr1 = *(const float4*)(Wsrc + 4),
           wr2 = *(const float4*)(Wsrc + 8),  wr3 = *(const float4*)(Wsrc + 12);
    f32x4 acc = {0.f, 0.f, 0.f, 0.f};
    int r15 = lane & 15, hgrp = (lane >> 4) << 3;
    for (int kt = 0; kt < 4; ++kt) {
        if (kt) __syncthreads();
        store_one(&Ah[rowA][kA], &Al[rowA][kA], ar0);
        store_pair(&Wh[rowW][kW],     &Wl[rowW][kW],     wr0, wr1);
        store_pair(&Wh[rowW][kW + 8], &Wl[rowW][kW + 8], wr2, wr3);
        __syncthreads();
        if (kt < 3) {
            int ko = (kt + 1) * 64;
            ar0 = *(const float4*)(Asrc + ko);
            wr0 = *(const float4*)(Wsrc + ko);      wr1 = *(const float4*)(Wsrc + ko + 4);
            wr2 = *(const float4*)(Wsrc + ko + 8);  wr3 = *(const float4*)(Wsrc + ko + 12);
        }
#pragma unroll
        for (int s = 0; s < 2; ++s) {
            int ko = s * 32 + hgrp;
            bf16x8 ah = *(const bf16x8*)&Ah[r15][ko];
            bf16x8 al = *(const bf16x8*)&Al[r15][ko];
            bf16x8 bh = *(const bf16x8*)&Wh[w * 16 + r15][ko];
            bf16x8 bl = *(const bf16x8*)&Wl[w * 16 + r15][ko];
            acc = __builtin_amdgcn_mfma_f32_16x16x32_bf16(ah, bh, acc, 0, 0, 0);
            acc = __builtin_amdgcn_mfma_f32_16x16x32_bf16(ah, bl, acc, 0, 0, 0);
            acc = __builtin_amdgcn_mfma_f32_16x16x32_bf16(al, bh, acc, 0, 0, 0);
        }
    }
    {
        int col = n0 + w * 16 + r15;
        int rowb = m0 + ((lane >> 4) << 2);
        float bcol = J.bias[col];
#pragma unroll
        for (int rr = 0; rr < 4; ++rr) {
            int m = rowb + rr;
            float v = acc[rr] + bcol;
            if (J.pos) v += J.pos[(m & 255) * 256 + col];
            if (J.relu) v = fmaxf(v, 0.f);
            if (J.res) v += J.res[m * 256 + col];
            if (J.maskm && J.maskm[m]) v = 0.f;
            J.C[m * 256 + col] = v;
        }
    }
}

// PAIRED attn (r20 exact — best measured): qA=2P, qB=2P+1 share K/V-row loads (25%
// L2 traffic cut). 1024 blocks, b=bid&7 keeps XCD affinity; pair map bijective,
// per-CU row sum exactly 1028. launch_bounds(256,4): 128-VGPR budget, batch-2 cannot
// spill. r20/r21/r22 proved dur invariant (42.4us) across occupancy 25/41/51% —
// structural floor; do not touch. Softmax writes e=0 for invalid k.
__global__ __launch_bounds__(256, 4) void attn_kernel(
    const float* __restrict__ Q, const float* __restrict__ Kp, const float* __restrict__ Vp,
    const float* __restrict__ qres, const int* __restrict__ tm,
    const float* __restrict__ tK, const float* __restrict__ tV,
    const float* __restrict__ g2, const float* __restrict__ b2,
    float* __restrict__ X2) {
    int bid = (int)blockIdx.x;
    int b = bid & 7;                    // XCD-aligned batch
    int i6 = bid >> 3;                  // 0..127
    int j = i6 & 31, a = i6 >> 5;
    int base = 2 * j + (a >> 1);        // 0..63
    int P = (a & 1) ? base : 127 - base;
    int qA = 2 * P, qB = 2 * P + 1;
    int tid = threadIdx.x, w = tid >> 6, lane = tid & 63;
    __shared__ float qrow[2][256];
    __shared__ int   stm[2][256];
    __shared__ float p[2][4][264];
    __shared__ float opart[2][4][256];
    __shared__ float denom[2][4];
    __shared__ float lnws[2][8];

    int rowbaseA = (b * 256 + qA) * 256;
    int rowbaseB = (b * 256 + qB) * 256;
    qrow[0][tid] = Q[rowbaseA + tid];
    qrow[1][tid] = Q[rowbaseB + tid];
    {
        int tA = tm[rowbaseA + tid];
        int tB = tm[rowbaseB + tid];
        stm[0][tid] = tA < 0 ? 0 : (tA > 512 ? 512 : tA);
        stm[1][tid] = tB < 0 ? 0 : (tB > 512 ? 512 : tB);
    }
    __syncthreads();

    // --- phase 1: scores for BOTH q over qB's range, k ≡ w (mod 4); batch-2
    {
        int h = lane >> 4;
        const float* qrA = &qrow[0][lane * 4];
        const float* qrB = &qrow[1][lane * 4];
        float qA0 = qrA[0], qA1 = qrA[1], qA2 = qrA[2], qA3 = qrA[3];
        float qB0 = qrB[0], qB1 = qrB[1], qB2 = qrB[2], qB3 = qrB[3];
        const float* Kb  = Kp + (size_t)(b << 8) * 256 + lane * 4;
        const float* tKb = tK + lane * 4;
        int nact = (qB >= w) ? ((qB - w) >> 2) + 1 : 0;
        int i = 0;
        for (; i + 2 <= nact; i += 2) {
            int k0 = w + 4 * i, k1 = k0 + 4;
            float4 kv0 = *(const float4*)(Kb + k0 * 256);
            float4 kv1 = *(const float4*)(Kb + k1 * 256);
            float4 tA0 = *(const float4*)(tKb + stm[0][k0] * 256);
            float4 tA1 = *(const float4*)(tKb + stm[0][k1] * 256);
            float4 tB0 = *(const float4*)(tKb + stm[1][k0] * 256);
            float4 tB1 = *(const float4*)(tKb + stm[1][k1] * 256);
            float sA0 = qA0 * (kv0.x + tA0.x) + qA1 * (kv0.y + tA0.y) + qA2 * (kv0.z + tA0.z) + qA3 * (kv0.w + tA0.w);
            float sA1 = qA0 * (kv1.x + tA1.x) + qA1 * (kv1.y + tA1.y) + qA2 * (kv1.z + tA1.z) + qA3 * (kv1.w + tA1.w);
            float sB0 = qB0 * (kv0.x + tB0.x) + qB1 * (kv0.y + tB0.y) + qB2 * (kv0.z + tB0.z) + qB3 * (kv0.w + tB0.w);
            float sB1 = qB0 * (kv1.x + tB1.x) + qB1 * (kv1.y + tB1.y) + qB2 * (kv1.z + tB1.z) + qB3 * (kv1.w + tB1.w);
            sA0 += __shfl_xor(sA0, 1, 64); sA1 += __shfl_xor(sA1, 1, 64);
            sB0 += __shfl_xor(sB0, 1, 64); sB1 += __shfl_xor(sB1, 1, 64);
            sA0 += __shfl_xor(sA0, 2, 64); sA1 += __shfl_xor(sA1, 2, 64);
            sB0 += __shfl_xor(sB0, 2, 64); sB1 += __shfl_xor(sB1, 2, 64);
            sA0 += __shfl_xor(sA0, 4, 64); sA1 += __shfl_xor(sA1, 4, 64);
            sB0 += __shfl_xor(sB0, 4, 64); sB1 += __shfl_xor(sB1, 4, 64);
            sA0 += __shfl_xor(sA0, 8, 64); sA1 += __shfl_xor(sA1, 8, 64);
            sB0 += __shfl_xor(sB0, 8, 64); sB1 += __shfl_xor(sB1, 8, 64);
            if ((lane & 15) == 0) {
                p[0][h][k0] = sA0 * 0.125f;
                p[0][h][k1] = sA1 * 0.125f;
                p[1][h][k0] = sB0 * 0.125f;
                p[1][h][k1] = sB1 * 0.125f;
            }
        }
        if (i < nact) {
            int k = w + 4 * i;
            float4 kv = *(const float4*)(Kb + k * 256);
            float4 tA4 = *(const float4*)(tKb + stm[0][k] * 256);
            float4 tB4 = *(const float4*)(tKb + stm[1][k] * 256);
            float sA = qA0 * (kv.x + tA4.x) + qA1 * (kv.y + tA4.y) + qA2 * (kv.z + tA4.z) + qA3 * (kv.w + tA4.w);
            float sB = qB0 * (kv.x + tB4.x) + qB1 * (kv.y + tB4.y) + qB2 * (kv.z + tB4.z) + qB3 * (kv.w + tB4.w);
            sA += __shfl_xor(sA, 1, 64); sB += __shfl_xor(sB, 1, 64);
            sA += __shfl_xor(sA, 2, 64); sB += __shfl_xor(sB, 2, 64);
            sA += __shfl_xor(sA, 4, 64); sB += __shfl_xor(sB, 4, 64);
            sA += __shfl_xor(sA, 8, 64); sB += __shfl_xor(sB, 8, 64);
            if ((lane & 15) == 0) {
                p[0][h][k] = sA * 0.125f;
                p[1][h][k] = sB * 0.125f;
            }
        }
    }
    __syncthreads();

    // --- softmax: wave w owns head w for BOTH q; invalid k -> e = 0
    {
        float* phA = &p[0][w][0];
        float* phB = &p[1][w][0];
        float a0 = (lane       <= qA) ? phA[lane      ] : BIG_NEG_F;
        float a1 = (lane + 64  <= qA) ? phA[lane + 64 ] : BIG_NEG_F;
        float a2 = (lane + 128 <= qA) ? phA[lane + 128] : BIG_NEG_F;
        float a3 = (lane + 192 <= qA) ? phA[lane + 192] : BIG_NEG_F;
        float b0 = (lane       <= qB) ? phB[lane      ] : BIG_NEG_F;
        float b1 = (lane + 64  <= qB) ? phB[lane + 64 ] : BIG_NEG_F;
        float b2v = (lane + 128 <= qB) ? phB[lane + 128] : BIG_NEG_F;
        float b3 = (lane + 192 <= qB) ? phB[lane + 192] : BIG_NEG_F;
        float mxA = wave_max(fmaxf(fmaxf(a0, a1), fmaxf(a2, a3)));
        float mxB = wave_max(fmaxf(fmaxf(b0, b1), fmaxf(b2v, b3)));
        float eA0 = (lane       <= qA) ? __expf(a0 - mxA) : 0.f;
        float eA1 = (lane + 64  <= qA) ? __expf(a1 - mxA) : 0.f;
        float eA2 = (lane + 128 <= qA) ? __expf(a2 - mxA) : 0.f;
        float eA3 = (lane + 192 <= qA) ? __expf(a3 - mxA) : 0.f;
        float eB0 = (lane       <= qB) ? __expf(b0 - mxB) : 0.f;
        float eB1 = (lane + 64  <= qB) ? __expf(b1 - mxB) : 0.f;
        float eB2 = (lane + 128 <= qB) ? __expf(b2v - mxB) : 0.f;
        float eB3 = (lane + 192 <= qB) ? __expf(b3 - mxB) : 0.f;
        phA[lane] = eA0; phA[lane + 64] = eA1; phA[lane + 128] = eA2; phA[lane + 192] = eA3;
        phB[lane] = eB0; phB[lane + 64] = eB1; phB[lane + 128] = eB2; phB[lane + 192] = eB3;
        float sumA = wave_sum(eA0 + eA1 + eA2 + eA3);
        float sumB = wave_sum(eB0 + eB1 + eB2 + eB3);
        if (lane == 0) { denom[0][w] = sumA; denom[1][w] = sumB; }
    }
    __syncthreads();

    // --- phase 3: PV for BOTH q over qB's range (p_A is 0 beyond qA); batch-2
    {
        int hh = lane >> 4;
        const float* Vb  = Vp + (size_t)(b << 8) * 256 + lane * 4;
        const float* tVb = tV + lane * 4;
        const float* prA = &p[0][hh][0];
        const float* prB = &p[1][hh][0];
        float4 aA0 = {0.f, 0.f, 0.f, 0.f}, aA1 = aA0, aB0 = aA0, aB1 = aA0;
        int cnt = (qB >= w) ? ((qB - w) >> 2) + 1 : 0;
        int i = 0;
        for (; i + 2 <= cnt; i += 2) {
            int k0 = w + 4 * i, k1 = k0 + 4;
            float pA0 = prA[k0], pA1 = prA[k1], pB0 = prB[k0], pB1 = prB[k1];
            float4 v0 = *(const float4*)(Vb + k0 * 256);
            float4 v1 = *(const float4*)(Vb + k1 * 256);
            float4 uA0 = *(const float4*)(tVb + stm[0][k0] * 256);
            float4 uA1 = *(const float4*)(tVb + stm[0][k1] * 256);
            float4 uB0 = *(const float4*)(tVb + stm[1][k0] * 256);
            float4 uB1 = *(const float4*)(tVb + stm[1][k1] * 256);
            aA0.x += pA0 * (v0.x + uA0.x); aA0.y += pA0 * (v0.y + uA0.y); aA0.z += pA0 * (v0.z + uA0.z); aA0.w += pA0 * (v0.w + uA0.w);
            aA1.x += pA1 * (v1.x + uA1.x); aA1.y += pA1 * (v1.y + uA1.y); aA1.z += pA1 * (v1.z + uA1.z); aA1.w += pA1 * (v1.w + uA1.w);
            aB0.x += pB0 * (v0.x + uB0.x); aB0.y += pB0 * (v0.y + uB0.y); aB0.z += pB0 * (v0.z + uB0.z); aB0.w += pB0 * (v0.w + uB0.w);
            aB1.x += pB1 * (v1.x + uB1.x); aB1.y += pB1 * (v1.y + uB1.y); aB1.z += pB1 * (v1.z + uB1.z); aB1.w += pB1 * (v1.w + uB1.w);
        }
        if (i < cnt) {
            int k2 = w + 4 * i;
            float pA = prA[k2], pB = prB[k2];
            float4 v = *(const float4*)(Vb + k2 * 256);
            float4 uA = *(const float4*)(tVb + stm[0][k2] * 256);
            float4 uB = *(const float4*)(tVb + stm[1][k2] * 256);
            aA0.x += pA * (v.x + uA.x); aA0.y += pA * (v.y + uA.y);
            aA0.z += pA * (v.z + uA.z); aA0.w += pA * (v.w + uA.w);
            aB0.x += pB * (v.x + uB.x); aB0.y += pB * (v.y + uB.y);
            aB0.z += pB * (v.z + uB.z); aB0.w += pB * (v.w + uB.w);
        }
        float4 oA, oB;
        oA.x = aA0.x + aA1.x; oA.y = aA0.y + aA1.y; oA.z = aA0.z + aA1.z; oA.w = aA0.w + aA1.w;
        oB.x = aB0.x + aB1.x; oB.y = aB0.y + aB1.y; oB.z = aB0.z + aB1.z; oB.w = aB0.w + aB1.w;
        *(float4*)&opart[0][w][lane * 4] = oA;
        *(float4*)&opart[1][w][lane * 4] = oB;
    }
    __syncthreads();

    // --- combine + fused ln2 for both rows (parallel per thread, 2 barriers)
    {
        int d = tid, h = tid >> 6;
        float totA = opart[0][0][d] + opart[0][1][d] + opart[0][2][d] + opart[0][3][d];
        float totB = opart[1][0][d] + opart[1][1][d] + opart[1][2][d] + opart[1][3][d];
        float xvA = qres[rowbaseA + d] + totA / denom[0][h];
        float xvB = qres[rowbaseB + d] + totB / denom[1][h];
        float sA = wave_sum(xvA);
        float sB = wave_sum(xvB);
        if (lane == 0) { lnws[0][w] = sA; lnws[1][w] = sB; }
        __syncthreads();
        float meanA = (lnws[0][0] + lnws[0][1] + lnws[0][2] + lnws[0][3]) * (1.f / 256.f);
        float meanB = (lnws[1][0] + lnws[1][1] + lnws[1][2] + lnws[1][3]) * (1.f / 256.f);
        float ddA = xvA - meanA, ddB = xvB - meanB;
        float s2A = wave_sum(ddA * ddA);
        float s2B = wave_sum(ddB * ddB);
        if (lane == 0) { lnws[0][4 + w] = s2A; lnws[1][4 + w] = s2B; }
        __syncthreads();
        float varA = (lnws[0][4] + lnws[0][5] + lnws[0][6] + lnws[0][7]) * (1.f / 256.f);
        float varB = (lnws[1][4] + lnws[1][5] + lnws[1][6] + lnws[1][7]) * (1.f / 256.f);
        float gg = g2[d], bb = b2[d];
        X2[rowbaseA + d] = ddA / sqrtf(varA + 1e-8f) * gg + bb;
        X2[rowbaseB + d] = ddB / sqrtf(varB + 1e-8f) * gg + bb;
    }
}

extern "C" void kernel_launch(void* const* d_in, const int* in_sizes, int n_in,
                              void* d_out, int out_size, void* d_ws, size_t ws_size,
                              hipStream_t stream) {
    const unsigned char* mask_raw = (const unsigned char*)d_in[0];
    const float* seq  = (const float*)d_in[1];
    const int*   tm   = (const int*)d_in[3];
    const float* Wq   = (const float*)d_in[5];
    const float* bq   = (const float*)d_in[6];
    const float* Wk   = (const float*)d_in[7];
    const float* bk   = (const float*)d_in[8];
    const float* Wv   = (const float*)d_in[9];
    const float* bv   = (const float*)d_in[10];
    const float* ln1g = (const float*)d_in[11];
    const float* ln1b = (const float*)d_in[12];
    const float* ln2g = (const float*)d_in[13];
    const float* ln2b = (const float*)d_in[14];
    const float* W1   = (const float*)d_in[15];
    const float* b1   = (const float*)d_in[16];
    const float* W2   = (const float*)d_in[17];
    const float* b2   = (const float*)d_in[18];
    const float* posK = (const float*)d_in[19];
    const float* posV = (const float*)d_in[20];
    const float* tK   = (const float*)d_in[21];
    const float* tV   = (const float*)d_in[22];
    const float* lnfg = (const float*)d_in[23];
    const float* lnfb = (const float*)d_in[24];

    const int NEL = 8 * 256 * 256;
    float* x   = (float*)d_ws;
    float* q   = x   + NEL;
    float* Qb  = q   + NEL;
    float* KpB = Qb  + NEL;
    float* VpB = KpB + NEL;
    float* x2  = VpB + NEL;
    float* hb  = x2  + NEL;
    unsigned char* mask = (unsigned char*)(hb + NEL);

    dim3 gQKV(4, 64, 3);    // 32x64 tiles: 768 blocks = 3/CU
    dim3 gFFN16(4, 128);    // 16x64 tiles: 512 blocks = 2/CU

    prep_ln_kernel<<<512, 256, 0, stream>>>(seq, mask_raw, mask, x, q, ln1g, ln1b);
    for (int blk = 0; blk < 2; ++blk) {
        int o1 = blk * 256, oW = blk * 256 * 256;
        GemmJob jq = {q, Wq + oW, bq + o1, nullptr, nullptr, nullptr, Qb, 0};
        GemmJob jk = {x, Wk + oW, bk + o1, posK,    nullptr, nullptr, KpB, 0};
        GemmJob jv = {x, Wv + oW, bv + o1, posV,    nullptr, nullptr, VpB, 0};
        gemm_mfma_kernel<<<gQKV, 256, 0, stream>>>(jq, jk, jv);
        attn_kernel<<<1024, 256, 0, stream>>>(Qb, KpB, VpB, q, tm, tK, tV,
                                              ln2g + o1, ln2b + o1, x2);
        GemmJob f1 = {x2, W1 + oW, b1 + o1, nullptr, nullptr, nullptr, hb, 1};
        gemm_mfma16_kernel<<<gFFN16, 256, 0, stream>>>(f1);
        GemmJob f2 = {hb, W2 + oW, b2 + o1, nullptr, x2, mask, x, 0};
        gemm_mfma16_kernel<<<gFFN16, 256, 0, stream>>>(f2);
        if (blk == 0) ln_kernel<<<512, 256, 0, stream>>>(x, q, ln1g + 256, ln1b + 256);
    }
    ln_kernel<<<512, 256, 0, stream>>>(x, (float*)d_out, lnfg, lnfb);
}

// Round 24
// 231.701 us; speedup vs baseline: 1.0170x; 1.0097x over previous
//
#include <hip/hip_runtime.h>

#define BIG_NEG_F (-4294967296.0f)

typedef __attribute__((ext_vector_type(8))) short bf16x8;
typedef __attribute__((ext_vector_type(4))) float f32x4;

__device__ __forceinline__ float wave_sum(float v) {
#pragma unroll
    for (int m = 32; m; m >>= 1) v += __shfl_xor(v, m, 64);
    return v;
}
__device__ __forceinline__ float wave_max(float v) {
#pragma unroll
    for (int m = 32; m; m >>= 1) v = fmaxf(v, __shfl_xor(v, m, 64));
    return v;
}

__device__ __forceinline__ unsigned int pack2(float a, float b) {
    return (__float_as_uint(b) & 0xffff0000u) | (__float_as_uint(a) >> 16);
}
__device__ __forceinline__ float hipart(float x) {
    return __uint_as_float(__float_as_uint(x) & 0xffff0000u);
}
// split float4s into hi/lo bf16 (truncation split: hi exact-representable, lo = residual)
__device__ __forceinline__ void store_pair(unsigned short* hp, unsigned short* lp,
                                           float4 a, float4 b) {
    uint4 h;
    h.x = pack2(a.x, a.y); h.y = pack2(a.z, a.w);
    h.z = pack2(b.x, b.y); h.w = pack2(b.z, b.w);
    float lax = a.x - hipart(a.x), lay = a.y - hipart(a.y);
    float laz = a.z - hipart(a.z), law = a.w - hipart(a.w);
    float lbx = b.x - hipart(b.x), lby = b.y - hipart(b.y);
    float lbz = b.z - hipart(b.z), lbw = b.w - hipart(b.w);
    uint4 l;
    l.x = pack2(lax, lay); l.y = pack2(laz, law);
    l.z = pack2(lbx, lby); l.w = pack2(lbz, lbw);
    *(uint4*)hp = h;
    *(uint4*)lp = l;
}

// Fused prep: mask-mode detect (u8/i32/i64), x = seq*keep, q = ln1(x).
// WAVE-PER-ROW: 512 blocks x 4 waves; one wave = one row (64 lanes x float4).
__global__ __launch_bounds__(256) void prep_ln_kernel(const float* __restrict__ seq,
                                                      const unsigned char* __restrict__ mraw,
                                                      unsigned char* __restrict__ mout,
                                                      float* __restrict__ X, float* __restrict__ Q,
                                                      const float* __restrict__ g,
                                                      const float* __restrict__ be) {
    __shared__ int flags[2];
    int tid = threadIdx.x, w = tid >> 6, lane = tid & 63;
    if (tid == 0) { flags[0] = 0; flags[1] = 0; }
    __syncthreads();
    for (int i = tid; i < 2048; i += 256) {
        if (mraw[i]) {
            if (i & 3) atomicOr(&flags[0], 1);
            else if (i & 4) atomicOr(&flags[1], 1);
        }
    }
    __syncthreads();
    int mode = flags[0] ? 0 : (flags[1] ? 1 : 2);  // 0=u8, 1=i32, 2=i64
    int row = blockIdx.x * 4 + w;
    unsigned char mrow = (mode == 0) ? mraw[row] : (mode == 1) ? mraw[row * 4] : mraw[row * 8];
    if (lane == 0) mout[row] = mrow ? 1 : 0;
    int idx = row * 256 + lane * 4;
    float4 v;
    if (mrow) { v.x = 0.f; v.y = 0.f; v.z = 0.f; v.w = 0.f; }
    else v = *(const float4*)(seq + idx);
    *(float4*)(X + idx) = v;
    float mean = wave_sum(v.x + v.y + v.z + v.w) * (1.f / 256.f);
    float4 d;
    d.x = v.x - mean; d.y = v.y - mean; d.z = v.z - mean; d.w = v.w - mean;
    float var = wave_sum(d.x * d.x + d.y * d.y + d.z * d.z + d.w * d.w) * (1.f / 256.f);
    float inv = 1.f / sqrtf(var + 1e-8f);
    float4 gv = *(const float4*)(g + lane * 4);
    float4 bv = *(const float4*)(be + lane * 4);
    float4 o;
    o.x = d.x * inv * gv.x + bv.x;
    o.y = d.y * inv * gv.y + bv.y;
    o.z = d.z * inv * gv.z + bv.z;
    o.w = d.w * inv * gv.w + bv.w;
    *(float4*)(Q + idx) = o;
}

// WAVE-PER-ROW layernorm: 512 blocks x 4 waves, float4 loads, zero barriers.
__global__ __launch_bounds__(256) void ln_kernel(const float* __restrict__ X, float* __restrict__ Y,
                                                 const float* __restrict__ g,
                                                 const float* __restrict__ be) {
    int tid = threadIdx.x, w = tid >> 6, lane = tid & 63;
    int row = blockIdx.x * 4 + w;
    int idx = row * 256 + lane * 4;
    float4 v = *(const float4*)(X + idx);
    float mean = wave_sum(v.x + v.y + v.z + v.w) * (1.f / 256.f);
    float4 d;
    d.x = v.x - mean; d.y = v.y - mean; d.z = v.z - mean; d.w = v.w - mean;
    float var = wave_sum(d.x * d.x + d.y * d.y + d.z * d.z + d.w * d.w) * (1.f / 256.f);
    float inv = 1.f / sqrtf(var + 1e-8f);
    float4 gv = *(const float4*)(g + lane * 4);
    float4 bv = *(const float4*)(be + lane * 4);
    float4 o;
    o.x = d.x * inv * gv.x + bv.x;
    o.y = d.y * inv * gv.y + bv.y;
    o.z = d.z * inv * gv.z + bv.z;
    o.w = d.w * inv * gv.w + bv.w;
    *(float4*)(Y + idx) = o;
}

struct GemmJob {
    const float* A;            // [2048,256]
    const float* W;            // [256,256] row-major (out,in)
    const float* bias;         // [256]
    const float* pos;          // [256,256] per-position add, or null
    const float* res;          // residual add, or null
    const unsigned char* maskm;// row mask (zero out), or null
    float* C;                  // [2048,256]
    int relu;
};

// MFMA GEMM, 32x64 tile — the measured optimum for BOTH QKV and FFN (tile matrix fully
// explored: 64x64/32x64/16x64 x QKV/FFN, r15/r16/r17/r23 = 249/236.8/239.4/233.9 with
// 236.8-config best). 4 waves as 2Mx2N, each wave 16x32 (2 frags, 12 MFMA/K-tile).
// BK=64, split-precision bf16 (A·B ≈ Ah·Bh+Ah·Bl+Al·Bh, rel err ~2^-16), fragment
// layouts HW-verified r11. LDS 27.6KB. Register-prefetch of next K-tile under MFMAs.
__global__ __launch_bounds__(256) void gemm_mfma_kernel(GemmJob j0, GemmJob j1, GemmJob j2) {
    GemmJob J = (blockIdx.z == 0) ? j0 : (blockIdx.z == 1 ? j1 : j2);
    __shared__ unsigned short Ah[32][72], Al[32][72], Wh[64][72], Wl[64][72];
    int tid = threadIdx.x;
    int n0 = blockIdx.x * 64, m0 = blockIdx.y * 32;
    int w = tid >> 6, lane = tid & 63;
    int wm = w >> 1, wn = w & 1;
    int rowA = tid >> 3, kA = (tid & 7) * 8;    // A staging: 32 rows x 64 k, 8 floats/thread
    int rowW = tid >> 2, kW = (tid & 3) * 16;   // W staging: 64 rows x 64 k, 16 floats/thread
    const float* Asrc = J.A + (m0 + rowA) * 256 + kA;
    const float* Wsrc = J.W + (n0 + rowW) * 256 + kW;
    float4 ar0 = *(const float4*)(Asrc), ar1 = *(const float4*)(Asrc + 4);
    float4 wr0 = *(const float4*)(Wsrc),      wr1 = *(const float4*)(Wsrc + 4),
           wr2 = *(const float4*)(Wsrc + 8),  wr3 = *(const float4*)(Wsrc + 12);
    f32x4 acc[2] = {};
    int r15 = lane & 15, hgrp = (lane >> 4) << 3;
    for (int kt = 0; kt < 4; ++kt) {
        if (kt) __syncthreads();                // previous compute done before overwrite
        store_pair(&Ah[rowA][kA],     &Al[rowA][kA],     ar0, ar1);
        store_pair(&Wh[rowW][kW],     &Wl[rowW][kW],     wr0, wr1);
        store_pair(&Wh[rowW][kW + 8], &Wl[rowW][kW + 8], wr2, wr3);
        __syncthreads();
        if (kt < 3) {                           // prefetch next K-tile; retires under MFMAs
            int ko = (kt + 1) * 64;
            ar0 = *(const float4*)(Asrc + ko);      ar1 = *(const float4*)(Asrc + ko + 4);
            wr0 = *(const float4*)(Wsrc + ko);      wr1 = *(const float4*)(Wsrc + ko + 4);
            wr2 = *(const float4*)(Wsrc + ko + 8);  wr3 = *(const float4*)(Wsrc + ko + 12);
        }
#pragma unroll
        for (int s = 0; s < 2; ++s) {
            int ko = s * 32 + hgrp;
            bf16x8 ah = *(const bf16x8*)&Ah[wm * 16 + r15][ko];
            bf16x8 al = *(const bf16x8*)&Al[wm * 16 + r15][ko];
            bf16x8 bh0 = *(const bf16x8*)&Wh[wn * 32 + r15][ko];
            bf16x8 bh1 = *(const bf16x8*)&Wh[wn * 32 + 16 + r15][ko];
            bf16x8 bl0 = *(const bf16x8*)&Wl[wn * 32 + r15][ko];
            bf16x8 bl1 = *(const bf16x8*)&Wl[wn * 32 + 16 + r15][ko];
            acc[0] = __builtin_amdgcn_mfma_f32_16x16x32_bf16(ah, bh0, acc[0], 0, 0, 0);
            acc[0] = __builtin_amdgcn_mfma_f32_16x16x32_bf16(ah, bl0, acc[0], 0, 0, 0);
            acc[0] = __builtin_amdgcn_mfma_f32_16x16x32_bf16(al, bh0, acc[0], 0, 0, 0);
            acc[1] = __builtin_amdgcn_mfma_f32_16x16x32_bf16(ah, bh1, acc[1], 0, 0, 0);
            acc[1] = __builtin_amdgcn_mfma_f32_16x16x32_bf16(ah, bl1, acc[1], 0, 0, 0);
            acc[1] = __builtin_amdgcn_mfma_f32_16x16x32_bf16(al, bh1, acc[1], 0, 0, 0);
        }
    }
    // epilogue: C/D layout col=lane&15, row=(lane>>4)*4+rr
#pragma unroll
    for (int nf = 0; nf < 2; ++nf) {
        int col = n0 + wn * 32 + nf * 16 + r15;
        int rowb = m0 + wm * 16 + ((lane >> 4) << 2);
        float bcol = J.bias[col];
        f32x4 a = acc[nf];
#pragma unroll
        for (int rr = 0; rr < 4; ++rr) {
            int m = rowb + rr;
            float v = a[rr] + bcol;
            if (J.pos) v += J.pos[(m & 255) * 256 + col];
            if (J.relu) v = fmaxf(v, 0.f);
            if (J.res) v += J.res[m * 256 + col];
            if (J.maskm && J.maskm[m]) v = 0.f;
            J.C[m * 256 + col] = v;
        }
    }
}

// PAIRED attn (best measured — r20): qA=2P, qB=2P+1 share K/V-row loads (25% L2
// traffic cut). 1024 blocks, b=bid&7 keeps XCD affinity (working set ~2.3MB fits the
// 4MiB private L2); pair map bijective, per-CU row sum exactly 1028.
// launch_bounds(256,4): 128-VGPR budget, batch-2 cannot spill. r20/r21/r22 proved dur
// invariant (42.4us) across occupancy 25/41/51% — structural floor for this gather mix.
__global__ __launch_bounds__(256, 4) void attn_kernel(
    const float* __restrict__ Q, const float* __restrict__ Kp, const float* __restrict__ Vp,
    const float* __restrict__ qres, const int* __restrict__ tm,
    const float* __restrict__ tK, const float* __restrict__ tV,
    const float* __restrict__ g2, const float* __restrict__ b2,
    float* __restrict__ X2) {
    int bid = (int)blockIdx.x;
    int b = bid & 7;                    // XCD-aligned batch
    int i6 = bid >> 3;                  // 0..127
    int j = i6 & 31, a = i6 >> 5;
    int base = 2 * j + (a >> 1);        // 0..63
    int P = (a & 1) ? base : 127 - base;
    int qA = 2 * P, qB = 2 * P + 1;
    int tid = threadIdx.x, w = tid >> 6, lane = tid & 63;
    __shared__ float qrow[2][256];
    __shared__ int   stm[2][256];
    __shared__ float p[2][4][264];
    __shared__ float opart[2][4][256];
    __shared__ float denom[2][4];
    __shared__ float lnws[2][8];

    int rowbaseA = (b * 256 + qA) * 256;
    int rowbaseB = (b * 256 + qB) * 256;
    qrow[0][tid] = Q[rowbaseA + tid];
    qrow[1][tid] = Q[rowbaseB + tid];
    {
        int tA = tm[rowbaseA + tid];
        int tB = tm[rowbaseB + tid];
        stm[0][tid] = tA < 0 ? 0 : (tA > 512 ? 512 : tA);
        stm[1][tid] = tB < 0 ? 0 : (tB > 512 ? 512 : tB);
    }
    __syncthreads();

    // --- phase 1: scores for BOTH q over qB's range, k ≡ w (mod 4); batch-2
    {
        int h = lane >> 4;
        const float* qrA = &qrow[0][lane * 4];
        const float* qrB = &qrow[1][lane * 4];
        float qA0 = qrA[0], qA1 = qrA[1], qA2 = qrA[2], qA3 = qrA[3];
        float qB0 = qrB[0], qB1 = qrB[1], qB2 = qrB[2], qB3 = qrB[3];
        const float* Kb  = Kp + (size_t)(b << 8) * 256 + lane * 4;
        const float* tKb = tK + lane * 4;
        int nact = (qB >= w) ? ((qB - w) >> 2) + 1 : 0;
        int i = 0;
        for (; i + 2 <= nact; i += 2) {
            int k0 = w + 4 * i, k1 = k0 + 4;
            float4 kv0 = *(const float4*)(Kb + k0 * 256);
            float4 kv1 = *(const float4*)(Kb + k1 * 256);
            float4 tA0 = *(const float4*)(tKb + stm[0][k0] * 256);
            float4 tA1 = *(const float4*)(tKb + stm[0][k1] * 256);
            float4 tB0 = *(const float4*)(tKb + stm[1][k0] * 256);
            float4 tB1 = *(const float4*)(tKb + stm[1][k1] * 256);
            float sA0 = qA0 * (kv0.x + tA0.x) + qA1 * (kv0.y + tA0.y) + qA2 * (kv0.z + tA0.z) + qA3 * (kv0.w + tA0.w);
            float sA1 = qA0 * (kv1.x + tA1.x) + qA1 * (kv1.y + tA1.y) + qA2 * (kv1.z + tA1.z) + qA3 * (kv1.w + tA1.w);
            float sB0 = qB0 * (kv0.x + tB0.x) + qB1 * (kv0.y + tB0.y) + qB2 * (kv0.z + tB0.z) + qB3 * (kv0.w + tB0.w);
            float sB1 = qB0 * (kv1.x + tB1.x) + qB1 * (kv1.y + tB1.y) + qB2 * (kv1.z + tB1.z) + qB3 * (kv1.w + tB1.w);
            sA0 += __shfl_xor(sA0, 1, 64); sA1 += __shfl_xor(sA1, 1, 64);
            sB0 += __shfl_xor(sB0, 1, 64); sB1 += __shfl_xor(sB1, 1, 64);
            sA0 += __shfl_xor(sA0, 2, 64); sA1 += __shfl_xor(sA1, 2, 64);
            sB0 += __shfl_xor(sB0, 2, 64); sB1 += __shfl_xor(sB1, 2, 64);
            sA0 += __shfl_xor(sA0, 4, 64); sA1 += __shfl_xor(sA1, 4, 64);
            sB0 += __shfl_xor(sB0, 4, 64); sB1 += __shfl_xor(sB1, 4, 64);
            sA0 += __shfl_xor(sA0, 8, 64); sA1 += __shfl_xor(sA1, 8, 64);
            sB0 += __shfl_xor(sB0, 8, 64); sB1 += __shfl_xor(sB1, 8, 64);
            if ((lane & 15) == 0) {
                p[0][h][k0] = sA0 * 0.125f;
                p[0][h][k1] = sA1 * 0.125f;
                p[1][h][k0] = sB0 * 0.125f;
                p[1][h][k1] = sB1 * 0.125f;
            }
        }
        if (i < nact) {
            int k = w + 4 * i;
            float4 kv = *(const float4*)(Kb + k * 256);
            float4 tA4 = *(const float4*)(tKb + stm[0][k] * 256);
            float4 tB4 = *(const float4*)(tKb + stm[1][k] * 256);
            float sA = qA0 * (kv.x + tA4.x) + qA1 * (kv.y + tA4.y) + qA2 * (kv.z + tA4.z) + qA3 * (kv.w + tA4.w);
            float sB = qB0 * (kv.x + tB4.x) + qB1 * (kv.y + tB4.y) + qB2 * (kv.z + tB4.z) + qB3 * (kv.w + tB4.w);
            sA += __shfl_xor(sA, 1, 64); sB += __shfl_xor(sB, 1, 64);
            sA += __shfl_xor(sA, 2, 64); sB += __shfl_xor(sB, 2, 64);
            sA += __shfl_xor(sA, 4, 64); sB += __shfl_xor(sB, 4, 64);
            sA += __shfl_xor(sA, 8, 64); sB += __shfl_xor(sB, 8, 64);
            if ((lane & 15) == 0) {
                p[0][h][k] = sA * 0.125f;
                p[1][h][k] = sB * 0.125f;
            }
        }
    }
    __syncthreads();

    // --- softmax: wave w owns head w for BOTH q; invalid k -> e = 0
    {
        float* phA = &p[0][w][0];
        float* phB = &p[1][w][0];
        float a0 = (lane       <= qA) ? phA[lane      ] : BIG_NEG_F;
        float a1 = (lane + 64  <= qA) ? phA[lane + 64 ] : BIG_NEG_F;
        float a2 = (lane + 128 <= qA) ? phA[lane + 128] : BIG_NEG_F;
        float a3 = (lane + 192 <= qA) ? phA[lane + 192] : BIG_NEG_F;
        float b0 = (lane       <= qB) ? phB[lane      ] : BIG_NEG_F;
        float b1 = (lane + 64  <= qB) ? phB[lane + 64 ] : BIG_NEG_F;
        float b2v = (lane + 128 <= qB) ? phB[lane + 128] : BIG_NEG_F;
        float b3 = (lane + 192 <= qB) ? phB[lane + 192] : BIG_NEG_F;
        float mxA = wave_max(fmaxf(fmaxf(a0, a1), fmaxf(a2, a3)));
        float mxB = wave_max(fmaxf(fmaxf(b0, b1), fmaxf(b2v, b3)));
        float eA0 = (lane       <= qA) ? __expf(a0 - mxA) : 0.f;
        float eA1 = (lane + 64  <= qA) ? __expf(a1 - mxA) : 0.f;
        float eA2 = (lane + 128 <= qA) ? __expf(a2 - mxA) : 0.f;
        float eA3 = (lane + 192 <= qA) ? __expf(a3 - mxA) : 0.f;
        float eB0 = (lane       <= qB) ? __expf(b0 - mxB) : 0.f;
        float eB1 = (lane + 64  <= qB) ? __expf(b1 - mxB) : 0.f;
        float eB2 = (lane + 128 <= qB) ? __expf(b2v - mxB) : 0.f;
        float eB3 = (lane + 192 <= qB) ? __expf(b3 - mxB) : 0.f;
        phA[lane] = eA0; phA[lane + 64] = eA1; phA[lane + 128] = eA2; phA[lane + 192] = eA3;
        phB[lane] = eB0; phB[lane + 64] = eB1; phB[lane + 128] = eB2; phB[lane + 192] = eB3;
        float sumA = wave_sum(eA0 + eA1 + eA2 + eA3);
        float sumB = wave_sum(eB0 + eB1 + eB2 + eB3);
        if (lane == 0) { denom[0][w] = sumA; denom[1][w] = sumB; }
    }
    __syncthreads();

    // --- phase 3: PV for BOTH q over qB's range (p_A is 0 beyond qA); batch-2
    {
        int hh = lane >> 4;
        const float* Vb  = Vp + (size_t)(b << 8) * 256 + lane * 4;
        const float* tVb = tV + lane * 4;
        const float* prA = &p[0][hh][0];
        const float* prB = &p[1][hh][0];
        float4 aA0 = {0.f, 0.f, 0.f, 0.f}, aA1 = aA0, aB0 = aA0, aB1 = aA0;
        int cnt = (qB >= w) ? ((qB - w) >> 2) + 1 : 0;
        int i = 0;
        for (; i + 2 <= cnt; i += 2) {
            int k0 = w + 4 * i, k1 = k0 + 4;
            float pA0 = prA[k0], pA1 = prA[k1], pB0 = prB[k0], pB1 = prB[k1];
            float4 v0 = *(const float4*)(Vb + k0 * 256);
            float4 v1 = *(const float4*)(Vb + k1 * 256);
            float4 uA0 = *(const float4*)(tVb + stm[0][k0] * 256);
            float4 uA1 = *(const float4*)(tVb + stm[0][k1] * 256);
            float4 uB0 = *(const float4*)(tVb + stm[1][k0] * 256);
            float4 uB1 = *(const float4*)(tVb + stm[1][k1] * 256);
            aA0.x += pA0 * (v0.x + uA0.x); aA0.y += pA0 * (v0.y + uA0.y); aA0.z += pA0 * (v0.z + uA0.z); aA0.w += pA0 * (v0.w + uA0.w);
            aA1.x += pA1 * (v1.x + uA1.x); aA1.y += pA1 * (v1.y + uA1.y); aA1.z += pA1 * (v1.z + uA1.z); aA1.w += pA1 * (v1.w + uA1.w);
            aB0.x += pB0 * (v0.x + uB0.x); aB0.y += pB0 * (v0.y + uB0.y); aB0.z += pB0 * (v0.z + uB0.z); aB0.w += pB0 * (v0.w + uB0.w);
            aB1.x += pB1 * (v1.x + uB1.x); aB1.y += pB1 * (v1.y + uB1.y); aB1.z += pB1 * (v1.z + uB1.z); aB1.w += pB1 * (v1.w + uB1.w);
        }
        if (i < cnt) {
            int k2 = w + 4 * i;
            float pA = prA[k2], pB = prB[k2];
            float4 v = *(const float4*)(Vb + k2 * 256);
            float4 uA = *(const float4*)(tVb + stm[0][k2] * 256);
            float4 uB = *(const float4*)(tVb + stm[1][k2] * 256);
            aA0.x += pA * (v.x + uA.x); aA0.y += pA * (v.y + uA.y);
            aA0.z += pA * (v.z + uA.z); aA0.w += pA * (v.w + uA.w);
            aB0.x += pB * (v.x + uB.x); aB0.y += pB * (v.y + uB.y);
            aB0.z += pB * (v.z + uB.z); aB0.w += pB * (v.w + uB.w);
        }
        float4 oA, oB;
        oA.x = aA0.x + aA1.x; oA.y = aA0.y + aA1.y; oA.z = aA0.z + aA1.z; oA.w = aA0.w + aA1.w;
        oB.x = aB0.x + aB1.x; oB.y = aB0.y + aB1.y; oB.z = aB0.z + aB1.z; oB.w = aB0.w + aB1.w;
        *(float4*)&opart[0][w][lane * 4] = oA;
        *(float4*)&opart[1][w][lane * 4] = oB;
    }
    __syncthreads();

    // --- combine + fused ln2 for both rows (parallel per thread, 2 barriers)
    {
        int d = tid, h = tid >> 6;
        float totA = opart[0][0][d] + opart[0][1][d] + opart[0][2][d] + opart[0][3][d];
        float totB = opart[1][0][d] + opart[1][1][d] + opart[1][2][d] + opart[1][3][d];
        float xvA = qres[rowbaseA + d] + totA / denom[0][h];
        float xvB = qres[rowbaseB + d] + totB / denom[1][h];
        float sA = wave_sum(xvA);
        float sB = wave_sum(xvB);
        if (lane == 0) { lnws[0][w] = sA; lnws[1][w] = sB; }
        __syncthreads();
        float meanA = (lnws[0][0] + lnws[0][1] + lnws[0][2] + lnws[0][3]) * (1.f / 256.f);
        float meanB = (lnws[1][0] + lnws[1][1] + lnws[1][2] + lnws[1][3]) * (1.f / 256.f);
        float ddA = xvA - meanA, ddB = xvB - meanB;
        float s2A = wave_sum(ddA * ddA);
        float s2B = wave_sum(ddB * ddB);
        if (lane == 0) { lnws[0][4 + w] = s2A; lnws[1][4 + w] = s2B; }
        __syncthreads();
        float varA = (lnws[0][4] + lnws[0][5] + lnws[0][6] + lnws[0][7]) * (1.f / 256.f);
        float varB = (lnws[1][4] + lnws[1][5] + lnws[1][6] + lnws[1][7]) * (1.f / 256.f);
        float gg = g2[d], bb = b2[d];
        X2[rowbaseA + d] = ddA / sqrtf(varA + 1e-8f) * gg + bb;
        X2[rowbaseB + d] = ddB / sqrtf(varB + 1e-8f) * gg + bb;
    }
}

extern "C" void kernel_launch(void* const* d_in, const int* in_sizes, int n_in,
                              void* d_out, int out_size, void* d_ws, size_t ws_size,
                              hipStream_t stream) {
    const unsigned char* mask_raw = (const unsigned char*)d_in[0];
    const float* seq  = (const float*)d_in[1];
    const int*   tm   = (const int*)d_in[3];
    const float* Wq   = (const float*)d_in[5];
    const float* bq   = (const float*)d_in[6];
    const float* Wk   = (const float*)d_in[7];
    const float* bk   = (const float*)d_in[8];
    const float* Wv   = (const float*)d_in[9];
    const float* bv   = (const float*)d_in[10];
    const float* ln1g = (const float*)d_in[11];
    const float* ln1b = (const float*)d_in[12];
    const float* ln2g = (const float*)d_in[13];
    const float* ln2b = (const float*)d_in[14];
    const float* W1   = (const float*)d_in[15];
    const float* b1   = (const float*)d_in[16];
    const float* W2   = (const float*)d_in[17];
    const float* b2   = (const float*)d_in[18];
    const float* posK = (const float*)d_in[19];
    const float* posV = (const float*)d_in[20];
    const float* tK   = (const float*)d_in[21];
    const float* tV   = (const float*)d_in[22];
    const float* lnfg = (const float*)d_in[23];
    const float* lnfb = (const float*)d_in[24];

    const int NEL = 8 * 256 * 256;
    float* x   = (float*)d_ws;
    float* q   = x   + NEL;
    float* Qb  = q   + NEL;
    float* KpB = Qb  + NEL;
    float* VpB = KpB + NEL;
    float* x2  = VpB + NEL;
    float* hb  = x2  + NEL;
    unsigned char* mask = (unsigned char*)(hb + NEL);

    dim3 gQKV(4, 64, 3);   // 32x64 tiles: 768 blocks = 3/CU
    dim3 gFFN(4, 64, 1);   // 256 blocks = 1/CU

    prep_ln_kernel<<<512, 256, 0, stream>>>(seq, mask_raw, mask, x, q, ln1g, ln1b);
    for (int blk = 0; blk < 2; ++blk) {
        int o1 = blk * 256, oW = blk * 256 * 256;
        GemmJob jq = {q, Wq + oW, bq + o1, nullptr, nullptr, nullptr, Qb, 0};
        GemmJob jk = {x, Wk + oW, bk + o1, posK,    nullptr, nullptr, KpB, 0};
        GemmJob jv = {x, Wv + oW, bv + o1, posV,    nullptr, nullptr, VpB, 0};
        gemm_mfma_kernel<<<gQKV, 256, 0, stream>>>(jq, jk, jv);
        attn_kernel<<<1024, 256, 0, stream>>>(Qb, KpB, VpB, q, tm, tK, tV,
                                              ln2g + o1, ln2b + o1, x2);
        GemmJob f1 = {x2, W1 + oW, b1 + o1, nullptr, nullptr, nullptr, hb, 1};
        gemm_mfma_kernel<<<gFFN, 256, 0, stream>>>(f1, f1, f1);
        GemmJob f2 = {hb, W2 + oW, b2 + o1, nullptr, x2, mask, x, 0};
        gemm_mfma_kernel<<<gFFN, 256, 0, stream>>>(f2, f2, f2);
        if (blk == 0) ln_kernel<<<512, 256, 0, stream>>>(x, q, ln1g + 256, ln1b + 256);
    }
    ln_kernel<<<512, 256, 0, stream>>>(x, (float*)d_out, lnfg, lnfb);
}